// Round 11
// baseline (335.312 us; speedup 1.0000x reference)
//
#include <hip/hip_runtime.h>
#include <hip/hip_bf16.h>
#include <math.h>

#define B_ 32
#define T_ 2000
#define DE_ 512
#define DD_ 1024
#define A_ 128
#define FN_ 32
#define FS_ 16
#define KW_ (2*FS_+1)   // 33
#define NBX 32           // blocks per b in score grid (T_/BT)

typedef __bf16 bf16x8 __attribute__((ext_vector_type(8)));
typedef __bf16 bf16x4 __attribute__((ext_vector_type(4)));
typedef float f32x4 __attribute__((ext_vector_type(4)));

#define BT 64            // t-rows per score block
#define KC 32            // K columns per staged chunk (16 iterations)
#define LSTR 40          // loc tile LDS stride (bf16)

// async global->LDS, 16 B per lane; dest = lds base (wave-uniform) + lane*16
__device__ __forceinline__ void load_lds16(const void* g, void* l) {
    __builtin_amdgcn_global_load_lds(
        (const __attribute__((address_space(1))) unsigned int*)g,
        (__attribute__((address_space(3))) unsigned int*)l, 16, 0, 0);
}

__device__ __forceinline__ bf16x8 cvt8v(f32x4 x, f32x4 y) {
    bf16x8 o;
    o[0] = (__bf16)x[0]; o[1] = (__bf16)x[1]; o[2] = (__bf16)x[2]; o[3] = (__bf16)x[3];
    o[4] = (__bf16)y[0]; o[5] = (__bf16)y[1]; o[6] = (__bf16)y[2]; o[7] = (__bf16)y[3];
    return o;
}

// ---------------------------------------------------------------------------
// Kernel 1: prep.
//  blocks   0..63 : enc_w/att_w fp32->bf16
//  blocks  64..191: pdec[b][a] = att_b[a] + input_dec[b] . dec_w[a]
// ---------------------------------------------------------------------------
__global__ __launch_bounds__(256) void prep_kernel(
    const float* __restrict__ enc_w, const float* __restrict__ att_w,
    const float* __restrict__ input_dec, const float* __restrict__ dec_w,
    const float* __restrict__ att_b,
    __bf16* __restrict__ enc_bf, __bf16* __restrict__ att_bf,
    float* __restrict__ pdec)
{
    int bx = blockIdx.x, tid = threadIdx.x;
    if (bx < 64) {
        int i = bx * 256 + tid;                         // float4 index
        float4 v = ((const float4*)enc_w)[i];
        bf16x4 o;
        o[0] = (__bf16)v.x; o[1] = (__bf16)v.y; o[2] = (__bf16)v.z; o[3] = (__bf16)v.w;
        *(bf16x4*)(enc_bf + (size_t)i * 4) = o;
        if (i < (A_ * FN_) / 4) {
            float4 w = ((const float4*)att_w)[i];
            bf16x4 p;
            p[0] = (__bf16)w.x; p[1] = (__bf16)w.y; p[2] = (__bf16)w.z; p[3] = (__bf16)w.w;
            *(bf16x4*)(att_bf + (size_t)i * 4) = p;
        }
    } else {
        int pb = bx - 64;                               // 0..127
        int b  = pb >> 2;
        int a0 = (pb & 3) * 32;
        int al = tid >> 3;                              // 0..31
        int kg = tid & 7;                               // 0..7
        int a  = a0 + al;
        const float4* w = (const float4*)(dec_w + (size_t)a * DD_);
        const float4* x = (const float4*)(input_dec + (size_t)b * DD_);
        float acc = 0.f;
        #pragma unroll 8
        for (int j = 0; j < 32; j++) {
            int i4 = kg + j * 8;
            float4 wv = w[i4], xv = x[i4];
            acc += wv.x * xv.x + wv.y * xv.y + wv.z * xv.z + wv.w * xv.w;
        }
        acc += __shfl_xor(acc, 1, 64);
        acc += __shfl_xor(acc, 2, 64);
        acc += __shfl_xor(acc, 4, 64);
        if (kg == 0) pdec[b * A_ + a] = acc + att_b[a];
    }
}

// ---------------------------------------------------------------------------
// Kernel 2: score. One block = (b, 64 t-rows), 256 thr.
// GEMM structure = round-6 best (KC=32 dual-staged global_load_lds, dbuf,
// counted vmcnt(4), 4 blocks/CU, early-exit for fully-masked blocks).
// NEW: ZERO global atomics and NO in-score context pass. Block writes only
// its 64 unnormalized w values to wbuf and one denominator partial to
// dpart[b*NBX+bx] (plain store). Context moves to finalize (reads wbuf +
// L3-hot input_enc, deterministic order). Workspace stays in the proven
// 477 KB envelope (r10's 2.5 MB cpart exceeded it -> suspect OOB crash).
// Max-free softmax: w = exp(score - M), M = sum|out_w| (data-independent
// upper bound, identical in every block).
// ---------------------------------------------------------------------------
__global__ __launch_bounds__(256, 4) void score_kernel(
    const float* __restrict__ input_enc, const __bf16* __restrict__ enc_bf,
    const float* __restrict__ prev_att,  const float* __restrict__ conv_w,
    const __bf16* __restrict__ att_bf,   const float* __restrict__ pdec,
    const float* __restrict__ out_w,     const int* __restrict__ lengths,
    float* __restrict__ wbuf, float* __restrict__ dpart)
{
    __shared__ __align__(16) char At[2][8192];   // A dbuf: 64 rows x 32 f32 (128B/row, XOR-8 swz)
    __shared__ __align__(16) char Bt[2][8192];   // B dbuf: 128 rows x 32 bf16 (64B/row, XOR swz)
    __shared__ __align__(16) float pa_s[BT + 2 * FS_];
    __shared__ __align__(16) __bf16 loc_s[BT * LSTR];
    __shared__ float w_s[BT];

    const int tid  = threadIdx.x;
    const int lane = tid & 63;
    const int wv   = tid >> 6;
    const int b  = blockIdx.y;
    const int bx = blockIdx.x;
    const int t0 = bx * BT;
    const int len = lengths[b];
    const int slot = b * NBX + bx;

    // ---- early exit: block entirely past this utterance's length ----
    if (t0 >= len) {
        if (tid < BT) {
            int t = t0 + tid;
            if (t < T_) wbuf[b * T_ + t] = 0.f;
        }
        if (tid == 0) dpart[slot] = 0.f;
        return;
    }

    // ---- DMA issue: 2 A-loads + 2 B-loads per thread per K-step ----
    auto issueA = [&](int kc, int bufi) {
        #pragma unroll
        for (int j = 0; j < 2; j++) {
            int s  = j * 256 + tid;              // 0..511
            int r  = s >> 3;                     // row 0..63 (8 x 16B slots/row)
            int q  = s & 7;                      // phys 16B slot
            int cl = q ^ (r & 7);                // XOR-8 swizzle (source side)
            int t  = t0 + r; if (t > T_ - 1) t = T_ - 1;
            load_lds16(input_enc + ((size_t)(b * T_ + t)) * DE_ + kc + cl * 4,
                       At[bufi] + j * 4096 + wv * 1024);
        }
    };
    auto issueB = [&](int kc, int bufi) {
        #pragma unroll
        for (int j = 0; j < 2; j++) {
            int s  = j * 256 + tid;              // 0..511
            int r  = s >> 2;                     // row 0..127 (4 x 16B slots/row)
            int q  = s & 3;                      // phys slot
            int cl = q ^ ((r >> 1) & 3);         // swizzle: 2-way max conflict on read
            load_lds16(enc_bf + (size_t)r * DE_ + kc + cl * 8,
                       Bt[bufi] + j * 4096 + wv * 1024);
        }
    };

    // issue chunks 0 and 1 (latency covered by pa/conv phase)
    issueA(0, 0);   issueB(0, 0);
    issueA(KC, 1);  issueB(KC, 1);

    // conv weights for this thread's filter f: direct from global (L1-hot)
    const int f    = tid & 31;
    const int rblk = tid >> 5;                   // 0..7 -> rows rblk*8..rblk*8+7
    float cwr[KW_];
    #pragma unroll
    for (int k = 0; k < KW_; k++) cwr[k] = conv_w[f * KW_ + k];

    if (tid < BT + 2 * FS_) {
        int t = t0 - FS_ + tid;
        pa_s[tid] = (t >= 0 && t < T_) ? prev_att[b * T_ + t] : 0.f;
    }
    __syncthreads();                             // pa_s ready (drains DMAs 0,1)

    {   // conv -> loc (bf16), register-blocked: 8 consecutive rows per thread
        float par[40];
        #pragma unroll
        for (int j = 0; j < 10; j++)
            *(float4*)&par[j * 4] = *(const float4*)&pa_s[rblk * 8 + j * 4];
        float accv[8] = {0.f, 0.f, 0.f, 0.f, 0.f, 0.f, 0.f, 0.f};
        #pragma unroll
        for (int k = 0; k < KW_; k++) {
            float c = cwr[k];
            #pragma unroll
            for (int j = 0; j < 8; j++) accv[j] += par[j + k] * c;
        }
        #pragma unroll
        for (int j = 0; j < 8; j++)
            loc_s[(rblk * 8 + j) * LSTR + f] = (__bf16)accv[j];
    }
    __syncthreads();                             // loc_s ready

    const int col  = lane & 15;
    const int grp  = lane >> 4;
    const int rowb = wv * 16 + col;              // 0..63
    const int keyA = rowb & 7;                   // A-read swizzle key

    f32x4 acc[8];
    const f32x4 zero = (f32x4){0.f, 0.f, 0.f, 0.f};

    {   // loc-projection MFMA (K=32=FN)
        bf16x8 afrag = *(const bf16x8*)(loc_s + rowb * LSTR + grp * 8);
        #pragma unroll
        for (int i = 0; i < 8; i++) {
            bf16x8 bfrag = *(const bf16x8*)(att_bf + (size_t)(i * 16 + col) * FN_ + grp * 8);
            acc[i] = __builtin_amdgcn_mfma_f32_16x16x32_bf16(afrag, bfrag, zero, 0, 0, 0);
        }
    }

    auto compute = [&](const char* Ab, const char* Bb) {
        f32x4 v0 = *(const f32x4*)(Ab + rowb * 128 + ((grp * 2)     ^ keyA) * 16);
        f32x4 v1 = *(const f32x4*)(Ab + rowb * 128 + ((grp * 2 + 1) ^ keyA) * 16);
        bf16x8 af = cvt8v(v0, v1);               // cols kc+grp*8 .. +8
        #pragma unroll
        for (int i = 0; i < 8; i++) {
            int row = i * 16 + col;
            bf16x8 bfrag = *(const bf16x8*)(Bb + row * 64 + ((grp ^ ((row >> 1) & 3)) * 16));
            acc[i] = __builtin_amdgcn_mfma_f32_16x16x32_bf16(af, bfrag, acc[i], 0, 0, 0);
        }
    };

    // ---- K-loop: 2-deep global_load_lds pipeline, counted vmcnt ----
    #pragma unroll
    for (int it = 0; it < 16; ++it) {
        compute(At[it & 1], Bt[it & 1]);
        if (it == 15) break;
        __builtin_amdgcn_s_barrier();            // all waves done reading buf[it&1]
        if (it + 2 < 16) {
            issueA((it + 2) * KC, it & 1);       // overwrite just-consumed buffer
            issueB((it + 2) * KC, it & 1);
            asm volatile("s_waitcnt vmcnt(4)" ::: "memory");  // step it+1 done
        } else {
            asm volatile("s_waitcnt vmcnt(0)" ::: "memory");  // drain tail
        }
        __builtin_amdgcn_s_barrier();            // buf[(it+1)&1] visible to all
    }

    // epilogue: s = tanh(acc + bias) . out_w over a; M = sum|out_w|
    float s[4] = {0.f, 0.f, 0.f, 0.f};
    float Mabs = 0.f;
    #pragma unroll
    for (int i = 0; i < 8; i++) {
        int a = i * 16 + col;
        float ow = out_w[a];
        Mabs += fabsf(ow);
        float bias = pdec[b * A_ + a];
        #pragma unroll
        for (int r = 0; r < 4; r++) {
            float v = acc[i][r] + bias;
            v = fminf(fmaxf(v, -15.f), 15.f);
            float e = __expf(2.f * v);
            s[r] += ow * ((e - 1.f) / (e + 1.f));
        }
    }
    #pragma unroll
    for (int r = 0; r < 4; r++) {
        s[r] += __shfl_xor(s[r], 1, 64);
        s[r] += __shfl_xor(s[r], 2, 64);
        s[r] += __shfl_xor(s[r], 4, 64);
        s[r] += __shfl_xor(s[r], 8, 64);
    }
    Mabs += __shfl_xor(Mabs, 1, 64);
    Mabs += __shfl_xor(Mabs, 2, 64);
    Mabs += __shfl_xor(Mabs, 4, 64);
    Mabs += __shfl_xor(Mabs, 8, 64);    // same value & rounding in every wave

    if (col == 0) {
        #pragma unroll
        for (int r = 0; r < 4; r++) {
            int rl = wv * 16 + grp * 4 + r;
            int t = t0 + rl;
            float w = 0.f;
            if (t < len) w = __expf(s[r] - Mabs);
            w_s[rl] = w;
            if (t < T_) wbuf[b * T_ + t] = w;
        }
    }
    __syncthreads();

    // denominator partial -> private slot (wave 0; plain store, no atomic)
    if (tid < 64) {
        float w = w_s[tid];
        w += __shfl_xor(w, 1, 64);
        w += __shfl_xor(w, 2, 64);
        w += __shfl_xor(w, 4, 64);
        w += __shfl_xor(w, 8, 64);
        w += __shfl_xor(w, 16, 64);
        w += __shfl_xor(w, 32, 64);
        if (tid == 0) dpart[slot] = w;
    }
}

// ---------------------------------------------------------------------------
// Kernel 3: finalize.
//  blocks   0..63 : att = wbuf / denom (denom = deterministic 32-slot sum)
//  blocks  64..319: ctx[b, d0+col] = sum_t wbuf[b,t]*enc[b,t,d0+col] / denom
//                   (8 blocks per b x 64 d-cols; 4 t-groups reduced in LDS;
//                    input_enc is L3-hot from score; no atomics)
// ---------------------------------------------------------------------------
__global__ __launch_bounds__(256) void finalize_kernel(
    const float* __restrict__ wbuf, const float* __restrict__ input_enc,
    const int* __restrict__ lengths, const float* __restrict__ dpart,
    float* __restrict__ out)
{
    int bx = blockIdx.x, tid = threadIdx.x;
    if (bx < 64) {
        int i4 = bx * 256 + tid;
        if (i4 < (B_ * T_) / 4) {
            int b = i4 / (T_ / 4);
            float dsum = 0.f;
            #pragma unroll
            for (int s = 0; s < NBX; s++) dsum += dpart[b * NBX + s];
            float inv = 1.f / dsum;
            float4 w = ((const float4*)wbuf)[i4];
            w.x *= inv; w.y *= inv; w.z *= inv; w.w *= inv;
            ((float4*)(out + B_ * DE_))[i4] = w;
        }
    } else {
        __shared__ float red[4][64];
        int cb  = bx - 64;                       // 0..255
        int b   = cb >> 3;                       // 8 blocks per b
        int d0  = (cb & 7) * 64;
        int col = tid & 63;
        int tg  = tid >> 6;                      // 0..3
        int len = lengths[b];
        float dsum = 0.f;
        #pragma unroll
        for (int s = 0; s < NBX; s++) dsum += dpart[b * NBX + s];
        float inv = 1.f / dsum;
        const float* eb = input_enc + (size_t)(b * T_) * DE_ + d0 + col;
        const float* wb = wbuf + b * T_;
        float c = 0.f;
        for (int t = tg; t < len; t += 4)
            c += wb[t] * eb[(size_t)t * DE_];
        red[tg][col] = c;
        __syncthreads();
        if (tg == 0) {
            float v = red[0][col] + red[1][col] + red[2][col] + red[3][col];
            out[b * DE_ + d0 + col] = v * inv;
        }
    }
}

// ---------------------------------------------------------------------------
extern "C" void kernel_launch(void* const* d_in, const int* in_sizes, int n_in,
                              void* d_out, int out_size, void* d_ws, size_t ws_size,
                              hipStream_t stream)
{
    const float* input_enc   = (const float*)d_in[0];
    const int*   enc_lengths = (const int*)d_in[1];
    const float* input_dec   = (const float*)d_in[2];
    const float* prev_att    = (const float*)d_in[3];
    const float* conv_w      = (const float*)d_in[4];
    const float* enc_w       = (const float*)d_in[5];
    const float* dec_w       = (const float*)d_in[6];
    const float* att_w       = (const float*)d_in[7];
    const float* att_b       = (const float*)d_in[8];
    const float* out_w       = (const float*)d_in[9];

    float* out = (float*)d_out;                 // [0:B*DE) context, [B*DE:) att_weight
    char* ws = (char*)d_ws;
    float*  pdec   = (float*)ws;                              // 4096 f    (16384 B)
    float*  wbuf   = (float*)(ws + 16384);                    // 64000 f   (256000 B)
    __bf16* enc_bf = (__bf16*)(ws + 272384);                  // A*DE bf16 (131072 B)
    __bf16* att_bf = (__bf16*)(ws + 403456);                  // A*FN bf16 (8192 B)
    float*  dpart  = (float*)(ws + 411648);                   // 1024 f    (4096 B)
    // high-water: 415744 B -- inside the 477 KB envelope proven in r0-r9

    prep_kernel<<<192, 256, 0, stream>>>(enc_w, att_w, input_dec, dec_w, att_b,
                                         enc_bf, att_bf, pdec);

    dim3 sgrid(NBX, B_);
    score_kernel<<<sgrid, 256, 0, stream>>>(input_enc, enc_bf, prev_att, conv_w,
                                            att_bf, pdec, out_w, enc_lengths,
                                            wbuf, dpart);

    finalize_kernel<<<320, 256, 0, stream>>>(wbuf, input_enc, enc_lengths,
                                             dpart, out);
}

// Round 12
// 224.704 us; speedup vs baseline: 1.4922x; 1.4922x over previous
//
#include <hip/hip_runtime.h>
#include <hip/hip_bf16.h>
#include <math.h>

#define B_ 32
#define T_ 2000
#define DE_ 512
#define DD_ 1024
#define A_ 128
#define FN_ 32
#define FS_ 16
#define KW_ (2*FS_+1)   // 33
#define NBX 32           // blocks per b in score grid (T_/BT)

typedef __bf16 bf16x8 __attribute__((ext_vector_type(8)));
typedef __bf16 bf16x4 __attribute__((ext_vector_type(4)));
typedef float f32x4 __attribute__((ext_vector_type(4)));

#define BT 64            // t-rows per score block
#define KC 32            // K columns per staged chunk (16 iterations)
#define LSTR 40          // loc tile LDS stride (bf16)

// async global->LDS, 16 B per lane; dest = lds base (wave-uniform) + lane*16
__device__ __forceinline__ void load_lds16(const void* g, void* l) {
    __builtin_amdgcn_global_load_lds(
        (const __attribute__((address_space(1))) unsigned int*)g,
        (__attribute__((address_space(3))) unsigned int*)l, 16, 0, 0);
}

__device__ __forceinline__ bf16x8 cvt8v(f32x4 x, f32x4 y) {
    bf16x8 o;
    o[0] = (__bf16)x[0]; o[1] = (__bf16)x[1]; o[2] = (__bf16)x[2]; o[3] = (__bf16)x[3];
    o[4] = (__bf16)y[0]; o[5] = (__bf16)y[1]; o[6] = (__bf16)y[2]; o[7] = (__bf16)y[3];
    return o;
}

// ---------------------------------------------------------------------------
// Kernel 1: prep.
//  blocks   0..63 : enc_w/att_w fp32->bf16
//  blocks  64..191: pdec[b][a] = att_b[a] + input_dec[b] . dec_w[a]
//  blocks 192..208: zero 16416 floats at zq (= ctx_un+denom in atomic mode;
//                   harmlessly overwritten slice of cpart in private mode)
// ---------------------------------------------------------------------------
__global__ __launch_bounds__(256) void prep_kernel(
    const float* __restrict__ enc_w, const float* __restrict__ att_w,
    const float* __restrict__ input_dec, const float* __restrict__ dec_w,
    const float* __restrict__ att_b,
    __bf16* __restrict__ enc_bf, __bf16* __restrict__ att_bf,
    float* __restrict__ pdec, float* __restrict__ zq)
{
    int bx = blockIdx.x, tid = threadIdx.x;
    if (bx < 64) {
        int i = bx * 256 + tid;                         // float4 index
        float4 v = ((const float4*)enc_w)[i];
        bf16x4 o;
        o[0] = (__bf16)v.x; o[1] = (__bf16)v.y; o[2] = (__bf16)v.z; o[3] = (__bf16)v.w;
        *(bf16x4*)(enc_bf + (size_t)i * 4) = o;
        if (i < (A_ * FN_) / 4) {
            float4 w = ((const float4*)att_w)[i];
            bf16x4 p;
            p[0] = (__bf16)w.x; p[1] = (__bf16)w.y; p[2] = (__bf16)w.z; p[3] = (__bf16)w.w;
            *(bf16x4*)(att_bf + (size_t)i * 4) = p;
        }
    } else if (bx < 192) {
        int pb = bx - 64;                               // 0..127
        int b  = pb >> 2;
        int a0 = (pb & 3) * 32;
        int al = tid >> 3;                              // 0..31
        int kg = tid & 7;                               // 0..7
        int a  = a0 + al;
        const float4* w = (const float4*)(dec_w + (size_t)a * DD_);
        const float4* x = (const float4*)(input_dec + (size_t)b * DD_);
        float acc = 0.f;
        #pragma unroll 8
        for (int j = 0; j < 32; j++) {
            int i4 = kg + j * 8;
            float4 wv = w[i4], xv = x[i4];
            acc += wv.x * xv.x + wv.y * xv.y + wv.z * xv.z + wv.w * xv.w;
        }
        acc += __shfl_xor(acc, 1, 64);
        acc += __shfl_xor(acc, 2, 64);
        acc += __shfl_xor(acc, 4, 64);
        if (kg == 0) pdec[b * A_ + a] = acc + att_b[a];
    } else {
        int idx = (bx - 192) * 256 + tid;               // float4 index
        if (idx < (B_ * DE_ + B_) / 4 + 1)              // 16416 floats
            ((float4*)zq)[idx] = make_float4(0.f, 0.f, 0.f, 0.f);
    }
}

// ---------------------------------------------------------------------------
// Kernel 2: score + context partials. One block = (b, 64 t-rows), 256 thr.
// GEMM structure = round-6 best (KC=32 dual-staged global_load_lds, dbuf,
// counted vmcnt(4), 4 blocks/CU, early-exit for fully-masked blocks).
// MODE 0 (private): ZERO global atomics. Block stores its 512-float context
//   partial to cpart[(b*NBX+bx)*DE] (coalesced plain stores) and its denom
//   partial to dpart[b*NBX+bx]; finalize reduces 32 slots deterministically.
// MODE 1 (atomic fallback, r6-proven): atomicAdd into ctx_un/denom.
// Context pass reads the block's own 64x512 tile (L2-hot from the GEMM:
// r6 vs r11 FETCH_SIZE identical ~87MB -> zero extra HBM traffic).
// Max-free softmax: w = exp(score - M), M = sum|out_w| (data-independent
// upper bound, identical in every block).
// ---------------------------------------------------------------------------
template<int MODE>
__global__ __launch_bounds__(256, 4) void score_kernel(
    const float* __restrict__ input_enc, const __bf16* __restrict__ enc_bf,
    const float* __restrict__ prev_att,  const float* __restrict__ conv_w,
    const __bf16* __restrict__ att_bf,   const float* __restrict__ pdec,
    const float* __restrict__ out_w,     const int* __restrict__ lengths,
    float* __restrict__ wbuf, float* __restrict__ cq, float* __restrict__ dq)
{
    __shared__ __align__(16) char At[2][8192];   // A dbuf: 64 rows x 32 f32 (128B/row, XOR-8 swz)
    __shared__ __align__(16) char Bt[2][8192];   // B dbuf: 128 rows x 32 bf16 (64B/row, XOR swz)
    __shared__ __align__(16) float pa_s[BT + 2 * FS_];
    __shared__ __align__(16) __bf16 loc_s[BT * LSTR];
    __shared__ float w_s[BT];

    const int tid  = threadIdx.x;
    const int lane = tid & 63;
    const int wv   = tid >> 6;
    const int b  = blockIdx.y;
    const int bx = blockIdx.x;
    const int t0 = bx * BT;
    const int len = lengths[b];
    const int slot = b * NBX + bx;

    // ---- early exit: block entirely past this utterance's length ----
    if (t0 >= len) {
        if (tid < BT) {
            int t = t0 + tid;
            if (t < T_) wbuf[b * T_ + t] = 0.f;
        }
        if (MODE == 0) {
            *(float2*)(cq + (size_t)slot * DE_ + tid * 2) = make_float2(0.f, 0.f);
            if (tid == 0) dq[slot] = 0.f;
        }
        return;
    }

    // ---- DMA issue: 2 A-loads + 2 B-loads per thread per K-step ----
    auto issueA = [&](int kc, int bufi) {
        #pragma unroll
        for (int j = 0; j < 2; j++) {
            int s  = j * 256 + tid;              // 0..511
            int r  = s >> 3;                     // row 0..63 (8 x 16B slots/row)
            int q  = s & 7;                      // phys 16B slot
            int cl = q ^ (r & 7);                // XOR-8 swizzle (source side)
            int t  = t0 + r; if (t > T_ - 1) t = T_ - 1;
            load_lds16(input_enc + ((size_t)(b * T_ + t)) * DE_ + kc + cl * 4,
                       At[bufi] + j * 4096 + wv * 1024);
        }
    };
    auto issueB = [&](int kc, int bufi) {
        #pragma unroll
        for (int j = 0; j < 2; j++) {
            int s  = j * 256 + tid;              // 0..511
            int r  = s >> 2;                     // row 0..127 (4 x 16B slots/row)
            int q  = s & 3;                      // phys slot
            int cl = q ^ ((r >> 1) & 3);         // swizzle: 2-way max conflict on read
            load_lds16(enc_bf + (size_t)r * DE_ + kc + cl * 8,
                       Bt[bufi] + j * 4096 + wv * 1024);
        }
    };

    // issue chunks 0 and 1 (latency covered by pa/conv phase)
    issueA(0, 0);   issueB(0, 0);
    issueA(KC, 1);  issueB(KC, 1);

    // conv weights for this thread's filter f: direct from global (L1-hot)
    const int f    = tid & 31;
    const int rblk = tid >> 5;                   // 0..7 -> rows rblk*8..rblk*8+7
    float cwr[KW_];
    #pragma unroll
    for (int k = 0; k < KW_; k++) cwr[k] = conv_w[f * KW_ + k];

    if (tid < BT + 2 * FS_) {
        int t = t0 - FS_ + tid;
        pa_s[tid] = (t >= 0 && t < T_) ? prev_att[b * T_ + t] : 0.f;
    }
    __syncthreads();                             // pa_s ready (drains DMAs 0,1)

    {   // conv -> loc (bf16), register-blocked: 8 consecutive rows per thread
        float par[40];
        #pragma unroll
        for (int j = 0; j < 10; j++)
            *(float4*)&par[j * 4] = *(const float4*)&pa_s[rblk * 8 + j * 4];
        float accv[8] = {0.f, 0.f, 0.f, 0.f, 0.f, 0.f, 0.f, 0.f};
        #pragma unroll
        for (int k = 0; k < KW_; k++) {
            float c = cwr[k];
            #pragma unroll
            for (int j = 0; j < 8; j++) accv[j] += par[j + k] * c;
        }
        #pragma unroll
        for (int j = 0; j < 8; j++)
            loc_s[(rblk * 8 + j) * LSTR + f] = (__bf16)accv[j];
    }
    __syncthreads();                             // loc_s ready

    const int col  = lane & 15;
    const int grp  = lane >> 4;
    const int rowb = wv * 16 + col;              // 0..63
    const int keyA = rowb & 7;                   // A-read swizzle key

    f32x4 acc[8];
    const f32x4 zero = (f32x4){0.f, 0.f, 0.f, 0.f};

    {   // loc-projection MFMA (K=32=FN)
        bf16x8 afrag = *(const bf16x8*)(loc_s + rowb * LSTR + grp * 8);
        #pragma unroll
        for (int i = 0; i < 8; i++) {
            bf16x8 bfrag = *(const bf16x8*)(att_bf + (size_t)(i * 16 + col) * FN_ + grp * 8);
            acc[i] = __builtin_amdgcn_mfma_f32_16x16x32_bf16(afrag, bfrag, zero, 0, 0, 0);
        }
    }

    auto compute = [&](const char* Ab, const char* Bb) {
        f32x4 v0 = *(const f32x4*)(Ab + rowb * 128 + ((grp * 2)     ^ keyA) * 16);
        f32x4 v1 = *(const f32x4*)(Ab + rowb * 128 + ((grp * 2 + 1) ^ keyA) * 16);
        bf16x8 af = cvt8v(v0, v1);               // cols kc+grp*8 .. +8
        #pragma unroll
        for (int i = 0; i < 8; i++) {
            int row = i * 16 + col;
            bf16x8 bfrag = *(const bf16x8*)(Bb + row * 64 + ((grp ^ ((row >> 1) & 3)) * 16));
            acc[i] = __builtin_amdgcn_mfma_f32_16x16x32_bf16(af, bfrag, acc[i], 0, 0, 0);
        }
    };

    // ---- K-loop: 2-deep global_load_lds pipeline, counted vmcnt ----
    #pragma unroll
    for (int it = 0; it < 16; ++it) {
        compute(At[it & 1], Bt[it & 1]);
        if (it == 15) break;
        __builtin_amdgcn_s_barrier();            // all waves done reading buf[it&1]
        if (it + 2 < 16) {
            issueA((it + 2) * KC, it & 1);       // overwrite just-consumed buffer
            issueB((it + 2) * KC, it & 1);
            asm volatile("s_waitcnt vmcnt(4)" ::: "memory");  // step it+1 done
        } else {
            asm volatile("s_waitcnt vmcnt(0)" ::: "memory");  // drain tail
        }
        __builtin_amdgcn_s_barrier();            // buf[(it+1)&1] visible to all
    }

    // epilogue: s = tanh(acc + bias) . out_w over a; M = sum|out_w|
    float s[4] = {0.f, 0.f, 0.f, 0.f};
    float Mabs = 0.f;
    #pragma unroll
    for (int i = 0; i < 8; i++) {
        int a = i * 16 + col;
        float ow = out_w[a];
        Mabs += fabsf(ow);
        float bias = pdec[b * A_ + a];
        #pragma unroll
        for (int r = 0; r < 4; r++) {
            float v = acc[i][r] + bias;
            v = fminf(fmaxf(v, -15.f), 15.f);
            float e = __expf(2.f * v);
            s[r] += ow * ((e - 1.f) / (e + 1.f));
        }
    }
    #pragma unroll
    for (int r = 0; r < 4; r++) {
        s[r] += __shfl_xor(s[r], 1, 64);
        s[r] += __shfl_xor(s[r], 2, 64);
        s[r] += __shfl_xor(s[r], 4, 64);
        s[r] += __shfl_xor(s[r], 8, 64);
    }
    Mabs += __shfl_xor(Mabs, 1, 64);
    Mabs += __shfl_xor(Mabs, 2, 64);
    Mabs += __shfl_xor(Mabs, 4, 64);
    Mabs += __shfl_xor(Mabs, 8, 64);    // same value & rounding in every wave

    if (col == 0) {
        #pragma unroll
        for (int r = 0; r < 4; r++) {
            int rl = wv * 16 + grp * 4 + r;
            int t = t0 + rl;
            float w = 0.f;
            if (t < len) w = __expf(s[r] - Mabs);
            w_s[rl] = w;
            if (t < T_) wbuf[b * T_ + t] = w;
        }
    }
    __syncthreads();

    // denominator partial (wave 0)
    if (tid < 64) {
        float w = w_s[tid];
        w += __shfl_xor(w, 1, 64);
        w += __shfl_xor(w, 2, 64);
        w += __shfl_xor(w, 4, 64);
        w += __shfl_xor(w, 8, 64);
        w += __shfl_xor(w, 16, 64);
        w += __shfl_xor(w, 32, 64);
        if (tid == 0) {
            if (MODE == 0) dq[slot] = w;
            else           atomicAdd(&dq[b], w);
        }
    }

    // context partial: block's own 64x512 tile, L2-hot from the GEMM reads
    {
        int n_eff = len - t0;
        if (n_eff > BT) n_eff = BT;
        int d0 = tid * 2;
        const float* ebase = input_enc + ((size_t)(b * T_ + t0)) * DE_ + d0;
        float cx = 0.f, cy = 0.f;
        #pragma unroll 8
        for (int t = 0; t < n_eff; t++) {
            float w = w_s[t];
            float2 v = *(const float2*)(ebase + (size_t)t * DE_);
            cx += w * v.x;
            cy += w * v.y;
        }
        if (MODE == 0) {
            *(float2*)(cq + (size_t)slot * DE_ + d0) = make_float2(cx, cy);
        } else {
            atomicAdd(&cq[b * DE_ + d0 + 0], cx);
            atomicAdd(&cq[b * DE_ + d0 + 1], cy);
        }
    }
}

// ---------------------------------------------------------------------------
// Kernel 3: finalize.
// MODE 0: denom = deterministic 32-slot sum; ctx = 32-slot reduce of cpart.
// MODE 1: r6-proven (ctx_un/denom divide).
//  blocks 0..63: att = wbuf/denom; 64..79: ctx
// ---------------------------------------------------------------------------
template<int MODE>
__global__ __launch_bounds__(256) void finalize_kernel(
    const float* __restrict__ wbuf, const float* __restrict__ cq,
    const float* __restrict__ dq, float* __restrict__ out)
{
    int bx = blockIdx.x, tid = threadIdx.x;
    if (bx < 64) {
        int i4 = bx * 256 + tid;
        if (i4 < (B_ * T_) / 4) {
            int b = i4 / (T_ / 4);
            float dsum;
            if (MODE == 0) {
                dsum = 0.f;
                #pragma unroll
                for (int s = 0; s < NBX; s++) dsum += dq[b * NBX + s];
            } else dsum = dq[b];
            float inv = 1.f / dsum;
            float4 w = ((const float4*)wbuf)[i4];
            w.x *= inv; w.y *= inv; w.z *= inv; w.w *= inv;
            ((float4*)(out + B_ * DE_))[i4] = w;
        }
    } else {
        int j4 = (bx - 64) * 256 + tid;         // 0..4095 float4 outputs
        int b  = j4 >> 7;                        // 128 float4 per b
        int d4 = j4 & 127;
        float dsum;
        if (MODE == 0) {
            dsum = 0.f;
            #pragma unroll
            for (int s = 0; s < NBX; s++) dsum += dq[b * NBX + s];
        } else dsum = dq[b];
        float inv = 1.f / dsum;
        if (MODE == 0) {
            float cx = 0.f, cy = 0.f, cz = 0.f, cw = 0.f;
            #pragma unroll 8
            for (int s = 0; s < NBX; s++) {
                float4 p = ((const float4*)cq)[(size_t)(b * NBX + s) * (DE_ / 4) + d4];
                cx += p.x; cy += p.y; cz += p.z; cw += p.w;
            }
            ((float4*)out)[j4] = make_float4(cx * inv, cy * inv, cz * inv, cw * inv);
        } else {
            float4 c = ((const float4*)cq)[j4];
            c.x *= inv; c.y *= inv; c.z *= inv; c.w *= inv;
            ((float4*)out)[j4] = c;
        }
    }
}

// ---------------------------------------------------------------------------
extern "C" void kernel_launch(void* const* d_in, const int* in_sizes, int n_in,
                              void* d_out, int out_size, void* d_ws, size_t ws_size,
                              hipStream_t stream)
{
    const float* input_enc   = (const float*)d_in[0];
    const int*   enc_lengths = (const int*)d_in[1];
    const float* input_dec   = (const float*)d_in[2];
    const float* prev_att    = (const float*)d_in[3];
    const float* conv_w      = (const float*)d_in[4];
    const float* enc_w       = (const float*)d_in[5];
    const float* dec_w       = (const float*)d_in[6];
    const float* att_w       = (const float*)d_in[7];
    const float* att_b       = (const float*)d_in[8];
    const float* out_w       = (const float*)d_in[9];

    float* out = (float*)d_out;                 // [0:B*DE) context, [B*DE:) att_weight
    char* ws = (char*)d_ws;
    float*  pdec   = (float*)ws;                              // 4096 f    (16384 B)
    float*  wbuf   = (float*)(ws + 16384);                    // 64000 f   (256000 B)
    __bf16* enc_bf = (__bf16*)(ws + 272384);                  // A*DE bf16 (131072 B)
    __bf16* att_bf = (__bf16*)(ws + 403456);                  // A*FN bf16 (8192 B)
    float*  region = (float*)(ws + 411648);                   // cpart(2MB) or ctx_un+denom
    float*  dpart  = (float*)(ws + 2508800);                  // 1024 f (private mode)
    float*  denom  = (float*)(ws + 477184);                   // 32 f   (atomic mode)

    const bool priv = ws_size >= (size_t)2512896;             // 2 MB cpart + dpart fits

    prep_kernel<<<209, 256, 0, stream>>>(enc_w, att_w, input_dec, dec_w, att_b,
                                         enc_bf, att_bf, pdec, region);

    dim3 sgrid(NBX, B_);
    if (priv) {
        score_kernel<0><<<sgrid, 256, 0, stream>>>(input_enc, enc_bf, prev_att,
            conv_w, att_bf, pdec, out_w, enc_lengths, wbuf, region, dpart);
        finalize_kernel<0><<<80, 256, 0, stream>>>(wbuf, region, dpart, out);
    } else {
        score_kernel<1><<<sgrid, 256, 0, stream>>>(input_enc, enc_bf, prev_att,
            conv_w, att_bf, pdec, out_w, enc_lengths, wbuf, region, denom);
        finalize_kernel<1><<<80, 256, 0, stream>>>(wbuf, region, denom, out);
    }
}

// Round 13
// 223.911 us; speedup vs baseline: 1.4975x; 1.0035x over previous
//
#include <hip/hip_runtime.h>
#include <hip/hip_bf16.h>
#include <math.h>

#define B_ 32
#define T_ 2000
#define DE_ 512
#define DD_ 1024
#define A_ 128
#define FN_ 32
#define FS_ 16
#define KW_ (2*FS_+1)   // 33

typedef __bf16 bf16x8 __attribute__((ext_vector_type(8)));
typedef __bf16 bf16x4 __attribute__((ext_vector_type(4)));
typedef float f32x4 __attribute__((ext_vector_type(4)));

#define BT 64            // t-rows per score block
#define KC 32            // K columns per staged chunk (16 iterations)
#define LSTR 40          // loc tile LDS stride (bf16)

// async global->LDS, 16 B per lane; dest = lds base (wave-uniform) + lane*16
__device__ __forceinline__ void load_lds16(const void* g, void* l) {
    __builtin_amdgcn_global_load_lds(
        (const __attribute__((address_space(1))) unsigned int*)g,
        (__attribute__((address_space(3))) unsigned int*)l, 16, 0, 0);
}

__device__ __forceinline__ bf16x8 cvt8v(f32x4 x, f32x4 y) {
    bf16x8 o;
    o[0] = (__bf16)x[0]; o[1] = (__bf16)x[1]; o[2] = (__bf16)x[2]; o[3] = (__bf16)x[3];
    o[4] = (__bf16)y[0]; o[5] = (__bf16)y[1]; o[6] = (__bf16)y[2]; o[7] = (__bf16)y[3];
    return o;
}

// ---------------------------------------------------------------------------
// Kernel 1: prep.
//  blocks   0..63 : enc_w/att_w fp32->bf16
//  blocks  64..191: pdec[b][a] = att_b[a] + input_dec[b] . dec_w[a]
//  blocks 192..208: zero ctx_un (16384 f) + denom (32 f)
// ---------------------------------------------------------------------------
__global__ __launch_bounds__(256) void prep_kernel(
    const float* __restrict__ enc_w, const float* __restrict__ att_w,
    const float* __restrict__ input_dec, const float* __restrict__ dec_w,
    const float* __restrict__ att_b,
    __bf16* __restrict__ enc_bf, __bf16* __restrict__ att_bf,
    float* __restrict__ pdec, float* __restrict__ ctx_un /* denom follows */)
{
    int bx = blockIdx.x, tid = threadIdx.x;
    if (bx < 64) {
        int i = bx * 256 + tid;                         // float4 index
        float4 v = ((const float4*)enc_w)[i];
        bf16x4 o;
        o[0] = (__bf16)v.x; o[1] = (__bf16)v.y; o[2] = (__bf16)v.z; o[3] = (__bf16)v.w;
        *(bf16x4*)(enc_bf + (size_t)i * 4) = o;
        if (i < (A_ * FN_) / 4) {
            float4 w = ((const float4*)att_w)[i];
            bf16x4 p;
            p[0] = (__bf16)w.x; p[1] = (__bf16)w.y; p[2] = (__bf16)w.z; p[3] = (__bf16)w.w;
            *(bf16x4*)(att_bf + (size_t)i * 4) = p;
        }
    } else if (bx < 192) {
        int pb = bx - 64;                               // 0..127
        int b  = pb >> 2;
        int a0 = (pb & 3) * 32;
        int al = tid >> 3;                              // 0..31
        int kg = tid & 7;                               // 0..7
        int a  = a0 + al;
        const float4* w = (const float4*)(dec_w + (size_t)a * DD_);
        const float4* x = (const float4*)(input_dec + (size_t)b * DD_);
        float acc = 0.f;
        #pragma unroll 8
        for (int j = 0; j < 32; j++) {
            int i4 = kg + j * 8;
            float4 wv = w[i4], xv = x[i4];
            acc += wv.x * xv.x + wv.y * xv.y + wv.z * xv.z + wv.w * xv.w;
        }
        acc += __shfl_xor(acc, 1, 64);
        acc += __shfl_xor(acc, 2, 64);
        acc += __shfl_xor(acc, 4, 64);
        if (kg == 0) pdec[b * A_ + a] = acc + att_b[a];
    } else {
        int idx = (bx - 192) * 256 + tid;               // float4 index
        if (idx < (B_ * DE_ + B_) / 4 + 1)              // 16416 floats -> 4104 f4
            ((float4*)ctx_un)[idx] = make_float4(0.f, 0.f, 0.f, 0.f);
    }
}

// ---------------------------------------------------------------------------
// Kernel 2: score + context partials. One block = (b, 64 t-rows), 256 thr.
// Best-measured configuration (223.7 us total): K-chunk 32 -> LDS 38.5 KB ->
// 4 blocks/CU = 4 waves/SIMD AND the whole grid co-resident in ONE round;
// blocks fully past len early-exit (write wbuf zeros, skip all work).
// Counted-vmcnt DMA pipeline: both operands staged via global_load_lds
// (cannot be register-sunk), double-buffered, 2-deep prefetch, raw s_barrier
// + s_waitcnt vmcnt(4) (never 0 in steady state). Each step issues exactly
// 4 DMAs (2 A + 2 B). K accumulation order fixed -> bit-identical output.
// Max-free softmax: w = exp(score - M), M = sum|out_w|. Block accumulates
// its 64x512 tile (L2-hot from the GEMM reads) into ctx_un + denom.
// ---------------------------------------------------------------------------
__global__ __launch_bounds__(256, 4) void score_kernel(
    const float* __restrict__ input_enc, const __bf16* __restrict__ enc_bf,
    const float* __restrict__ prev_att,  const float* __restrict__ conv_w,
    const __bf16* __restrict__ att_bf,   const float* __restrict__ pdec,
    const float* __restrict__ out_w,     const int* __restrict__ lengths,
    float* __restrict__ wbuf, float* __restrict__ ctx_un,
    float* __restrict__ denom)
{
    __shared__ __align__(16) char At[2][8192];   // A dbuf: 64 rows x 32 f32 (128B/row, XOR-8 swz)
    __shared__ __align__(16) char Bt[2][8192];   // B dbuf: 128 rows x 32 bf16 (64B/row, XOR swz)
    __shared__ __align__(16) float pa_s[BT + 2 * FS_];
    __shared__ __align__(16) __bf16 loc_s[BT * LSTR];
    __shared__ float w_s[BT];

    const int tid  = threadIdx.x;
    const int lane = tid & 63;
    const int wv   = tid >> 6;
    const int b  = blockIdx.y;
    const int t0 = blockIdx.x * BT;
    const int len = lengths[b];

    // ---- early exit: block entirely past this utterance's length ----
    if (t0 >= len) {
        if (tid < BT) {
            int t = t0 + tid;
            if (t < T_) wbuf[b * T_ + t] = 0.f;
        }
        return;
    }

    // ---- DMA issue: 2 A-loads + 2 B-loads per thread per K-step ----
    auto issueA = [&](int kc, int bufi) {
        #pragma unroll
        for (int j = 0; j < 2; j++) {
            int s  = j * 256 + tid;              // 0..511
            int r  = s >> 3;                     // row 0..63 (8 x 16B slots/row)
            int q  = s & 7;                      // phys 16B slot
            int cl = q ^ (r & 7);                // XOR-8 swizzle (source side)
            int t  = t0 + r; if (t > T_ - 1) t = T_ - 1;
            load_lds16(input_enc + ((size_t)(b * T_ + t)) * DE_ + kc + cl * 4,
                       At[bufi] + j * 4096 + wv * 1024);
        }
    };
    auto issueB = [&](int kc, int bufi) {
        #pragma unroll
        for (int j = 0; j < 2; j++) {
            int s  = j * 256 + tid;              // 0..511
            int r  = s >> 2;                     // row 0..127 (4 x 16B slots/row)
            int q  = s & 3;                      // phys slot
            int cl = q ^ ((r >> 1) & 3);         // swizzle: 2-way max conflict on read
            load_lds16(enc_bf + (size_t)r * DE_ + kc + cl * 8,
                       Bt[bufi] + j * 4096 + wv * 1024);
        }
    };

    // issue chunks 0 and 1 (latency covered by pa/conv phase)
    issueA(0, 0);   issueB(0, 0);
    issueA(KC, 1);  issueB(KC, 1);

    // conv weights for this thread's filter f: direct from global (L1-hot)
    const int f    = tid & 31;
    const int rblk = tid >> 5;                   // 0..7 -> rows rblk*8..rblk*8+7
    float cwr[KW_];
    #pragma unroll
    for (int k = 0; k < KW_; k++) cwr[k] = conv_w[f * KW_ + k];

    if (tid < BT + 2 * FS_) {
        int t = t0 - FS_ + tid;
        pa_s[tid] = (t >= 0 && t < T_) ? prev_att[b * T_ + t] : 0.f;
    }
    __syncthreads();                             // pa_s ready (drains DMAs 0,1)

    {   // conv -> loc (bf16), register-blocked: 8 consecutive rows per thread
        float par[40];
        #pragma unroll
        for (int j = 0; j < 10; j++)
            *(float4*)&par[j * 4] = *(const float4*)&pa_s[rblk * 8 + j * 4];
        float accv[8] = {0.f, 0.f, 0.f, 0.f, 0.f, 0.f, 0.f, 0.f};
        #pragma unroll
        for (int k = 0; k < KW_; k++) {
            float c = cwr[k];
            #pragma unroll
            for (int j = 0; j < 8; j++) accv[j] += par[j + k] * c;
        }
        #pragma unroll
        for (int j = 0; j < 8; j++)
            loc_s[(rblk * 8 + j) * LSTR + f] = (__bf16)accv[j];
    }
    __syncthreads();                             // loc_s ready

    const int col  = lane & 15;
    const int grp  = lane >> 4;
    const int rowb = wv * 16 + col;              // 0..63
    const int keyA = rowb & 7;                   // A-read swizzle key

    f32x4 acc[8];
    const f32x4 zero = (f32x4){0.f, 0.f, 0.f, 0.f};

    {   // loc-projection MFMA (K=32=FN)
        bf16x8 afrag = *(const bf16x8*)(loc_s + rowb * LSTR + grp * 8);
        #pragma unroll
        for (int i = 0; i < 8; i++) {
            bf16x8 bfrag = *(const bf16x8*)(att_bf + (size_t)(i * 16 + col) * FN_ + grp * 8);
            acc[i] = __builtin_amdgcn_mfma_f32_16x16x32_bf16(afrag, bfrag, zero, 0, 0, 0);
        }
    }

    auto compute = [&](const char* Ab, const char* Bb) {
        f32x4 v0 = *(const f32x4*)(Ab + rowb * 128 + ((grp * 2)     ^ keyA) * 16);
        f32x4 v1 = *(const f32x4*)(Ab + rowb * 128 + ((grp * 2 + 1) ^ keyA) * 16);
        bf16x8 af = cvt8v(v0, v1);               // cols kc+grp*8 .. +8
        #pragma unroll
        for (int i = 0; i < 8; i++) {
            int row = i * 16 + col;
            bf16x8 bfrag = *(const bf16x8*)(Bb + row * 64 + ((grp ^ ((row >> 1) & 3)) * 16));
            acc[i] = __builtin_amdgcn_mfma_f32_16x16x32_bf16(af, bfrag, acc[i], 0, 0, 0);
        }
    };

    // ---- K-loop: 2-deep global_load_lds pipeline, counted vmcnt ----
    #pragma unroll
    for (int it = 0; it < 16; ++it) {
        compute(At[it & 1], Bt[it & 1]);
        if (it == 15) break;
        __builtin_amdgcn_s_barrier();            // all waves done reading buf[it&1]
        if (it + 2 < 16) {
            issueA((it + 2) * KC, it & 1);       // overwrite just-consumed buffer
            issueB((it + 2) * KC, it & 1);
            asm volatile("s_waitcnt vmcnt(4)" ::: "memory");  // step it+1 done
        } else {
            asm volatile("s_waitcnt vmcnt(0)" ::: "memory");  // drain tail
        }
        __builtin_amdgcn_s_barrier();            // buf[(it+1)&1] visible to all
    }

    // epilogue: s = tanh(acc + bias) . out_w over a; M = sum|out_w|
    float s[4] = {0.f, 0.f, 0.f, 0.f};
    float Mabs = 0.f;
    #pragma unroll
    for (int i = 0; i < 8; i++) {
        int a = i * 16 + col;
        float ow = out_w[a];
        Mabs += fabsf(ow);
        float bias = pdec[b * A_ + a];
        #pragma unroll
        for (int r = 0; r < 4; r++) {
            float v = acc[i][r] + bias;
            v = fminf(fmaxf(v, -15.f), 15.f);
            float e = __expf(2.f * v);
            s[r] += ow * ((e - 1.f) / (e + 1.f));
        }
    }
    #pragma unroll
    for (int r = 0; r < 4; r++) {
        s[r] += __shfl_xor(s[r], 1, 64);
        s[r] += __shfl_xor(s[r], 2, 64);
        s[r] += __shfl_xor(s[r], 4, 64);
        s[r] += __shfl_xor(s[r], 8, 64);
    }
    Mabs += __shfl_xor(Mabs, 1, 64);
    Mabs += __shfl_xor(Mabs, 2, 64);
    Mabs += __shfl_xor(Mabs, 4, 64);
    Mabs += __shfl_xor(Mabs, 8, 64);    // same value & rounding in every wave

    if (col == 0) {
        #pragma unroll
        for (int r = 0; r < 4; r++) {
            int rl = wv * 16 + grp * 4 + r;
            int t = t0 + rl;
            float w = 0.f;
            if (t < len) w = __expf(s[r] - Mabs);
            w_s[rl] = w;
            if (t < T_) wbuf[b * T_ + t] = w;
        }
    }
    __syncthreads();

    // denominator partial (wave 0)
    if (tid < 64) {
        float w = w_s[tid];
        w += __shfl_xor(w, 1, 64);
        w += __shfl_xor(w, 2, 64);
        w += __shfl_xor(w, 4, 64);
        w += __shfl_xor(w, 8, 64);
        w += __shfl_xor(w, 16, 64);
        w += __shfl_xor(w, 32, 64);
        if (tid == 0) atomicAdd(&denom[b], w);
    }

    // context partial: tile rows are L2/L3-hot from the GEMM reads
    int n_eff = len - t0;
    if (n_eff > BT) n_eff = BT;
    if (n_eff > 0) {
        int d0 = tid * 2;
        const float* ebase = input_enc + ((size_t)(b * T_ + t0)) * DE_ + d0;
        float cx = 0.f, cy = 0.f;
        #pragma unroll 8
        for (int t = 0; t < n_eff; t++) {
            float w = w_s[t];
            float2 v = *(const float2*)(ebase + (size_t)t * DE_);
            cx += w * v.x;
            cy += w * v.y;
        }
        atomicAdd(&ctx_un[b * DE_ + d0 + 0], cx);
        atomicAdd(&ctx_un[b * DE_ + d0 + 1], cy);
    }
}

// ---------------------------------------------------------------------------
// Kernel 3: finalize. blocks 0..63: att = wbuf/denom; 64..79: ctx = ctx_un/denom
// ---------------------------------------------------------------------------
__global__ __launch_bounds__(256) void finalize_kernel(
    const float* __restrict__ wbuf, const float* __restrict__ ctx_un,
    const float* __restrict__ denom, float* __restrict__ out)
{
    int bx = blockIdx.x, tid = threadIdx.x;
    if (bx < 64) {
        int i4 = bx * 256 + tid;
        if (i4 < (B_ * T_) / 4) {
            int b = i4 / (T_ / 4);
            float inv = 1.f / denom[b];
            float4 w = ((const float4*)wbuf)[i4];
            w.x *= inv; w.y *= inv; w.z *= inv; w.w *= inv;
            ((float4*)(out + B_ * DE_))[i4] = w;
        }
    } else {
        int j = (bx - 64) * 256 + tid;          // 0..4095
        int b = j / (DE_ / 4);
        float inv = 1.f / denom[b];
        float4 c = ((const float4*)ctx_un)[j];
        c.x *= inv; c.y *= inv; c.z *= inv; c.w *= inv;
        ((float4*)out)[j] = c;
    }
}

// ---------------------------------------------------------------------------
extern "C" void kernel_launch(void* const* d_in, const int* in_sizes, int n_in,
                              void* d_out, int out_size, void* d_ws, size_t ws_size,
                              hipStream_t stream)
{
    const float* input_enc   = (const float*)d_in[0];
    const int*   enc_lengths = (const int*)d_in[1];
    const float* input_dec   = (const float*)d_in[2];
    const float* prev_att    = (const float*)d_in[3];
    const float* conv_w      = (const float*)d_in[4];
    const float* enc_w       = (const float*)d_in[5];
    const float* dec_w       = (const float*)d_in[6];
    const float* att_w       = (const float*)d_in[7];
    const float* att_b       = (const float*)d_in[8];
    const float* out_w       = (const float*)d_in[9];

    float* out = (float*)d_out;                 // [0:B*DE) context, [B*DE:) att_weight
    char* ws = (char*)d_ws;
    float*  pdec   = (float*)ws;                              // 4096 f   (16384 B)
    float*  wbuf   = (float*)(ws + 16384);                    // 64000 f  (256000 B)
    __bf16* enc_bf = (__bf16*)(ws + 272384);                  // A*DE bf16 (131072 B)
    __bf16* att_bf = (__bf16*)(ws + 403456);                  // A*FN bf16 (8192 B)
    float*  ctx_un = (float*)(ws + 411648);                   // 16384 f  (65536 B)
    float*  denom  = (float*)(ws + 477184);                   // 32 f

    prep_kernel<<<209, 256, 0, stream>>>(enc_w, att_w, input_dec, dec_w, att_b,
                                         enc_bf, att_bf, pdec, ctx_un);

    dim3 sgrid((T_ + BT - 1) / BT, B_);
    score_kernel<<<sgrid, 256, 0, stream>>>(input_enc, enc_bf, prev_att, conv_w,
                                            att_bf, pdec, out_w, enc_lengths,
                                            wbuf, ctx_un, denom);

    finalize_kernel<<<80, 256, 0, stream>>>(wbuf, ctx_un, denom, out);
}